// Round 1
// baseline (43.748 us; speedup 1.0000x reference)
//
#include <hip/hip_runtime.h>

typedef unsigned short ushort_t;
typedef unsigned int uint_t;
typedef __bf16 bf16x8 __attribute__((ext_vector_type(8)));
typedef float f32x4 __attribute__((ext_vector_type(4)));

#define H 256
#define RPB 16  // batch rows per block

// output layout (f32): [nb 4096][bdot 4096][y 4096*256][yy 4096*64]
#define NB_OFF 0
#define BDOT_OFF 4096
#define Y_OFF 8192
#define YY_OFF (8192 + 4096 * 256)

__device__ __forceinline__ ushort_t f2bf(float x) {
    union { float f; uint_t u; } c; c.f = x;
    uint_t r = (c.u + 0x7FFFu + ((c.u >> 16) & 1u)) >> 16;  // RNE
    return (ushort_t)r;
}
__device__ __forceinline__ float bf2f(ushort_t v) {
    union { uint_t u; float f; } c; c.u = ((uint_t)v) << 16;
    return c.f;
}

// ws layout (ushort/bf16 units)
#define O_W1b  0        // [256][64]   B for z-stage (orig layout)
#define O_W1T  16384    // [64][256]   W1T[i][g] = w1[g][i]
#define O_W2ab 32768    // [256][256]  orig
#define O_W2bb 98304
#define O_W3ab 163840
#define O_W2aT 229376   // W2aT[g][h] = w2a[h][g]
#define O_W2bT 294912
#define O_W3aT 360448   // W3aT[h][o] = w3a[o][h]
#define O_W3sb 425984   // [256][64] orig
#define O_W3sT 442368   // [64][256] W3sT[i][o] = w3s[o][i]

__global__ void prep_weights(const float* __restrict__ w1, const float* __restrict__ w2a,
                             const float* __restrict__ w2b, const float* __restrict__ w3a,
                             const float* __restrict__ w3s, ushort_t* __restrict__ ws) {
    int t = blockIdx.x * 256 + threadIdx.x;  // 0..65535
    if (t < 16384) {
        int r = t >> 6, c = t & 63;
        ushort_t v = f2bf(w1[t]);
        ws[O_W1b + t] = v;
        ws[O_W1T + c * 256 + r] = v;
        ushort_t s = f2bf(w3s[t]);
        ws[O_W3sb + t] = s;
        ws[O_W3sT + c * 256 + r] = s;
    }
    {
        int r = t >> 8, c = t & 255;
        ushort_t v;
        v = f2bf(w2a[t]); ws[O_W2ab + t] = v; ws[O_W2aT + c * 256 + r] = v;
        v = f2bf(w2b[t]); ws[O_W2bb + t] = v; ws[O_W2bT + c * 256 + r] = v;
        v = f2bf(w3a[t]); ws[O_W3ab + t] = v; ws[O_W3aT + c * 256 + r] = v;
    }
}

// one 16x16 output tile of A[16,K] @ B(K x 16 slice starting at col n0).
// A: bf16 in LDS, row stride STRA, column-XOR-swizzled (c ^ ((r&7)<<3)).
// B: bf16 in global, stored [n][k] row-major so each lane reads 8 contig k.
template <int K, int STRA>
__device__ __forceinline__ f32x4 tile_gemm(const ushort_t* sA, const ushort_t* __restrict__ B,
                                           int lane, int n0, f32x4 acc) {
    const int row = lane & 15;
    const int kq = (lane >> 4) << 3;  // k-offset of this lane's 8 elements
    const int sw = (row & 7) << 3;
    const ushort_t* aptr = sA + row * STRA;
    const ushort_t* bptr = B + (n0 + row) * K + kq;
#pragma unroll
    for (int kb = 0; kb < K; kb += 32) {
        bf16x8 a = *(const bf16x8*)(aptr + ((kb + kq) ^ sw));
        bf16x8 b = *(const bf16x8*)(bptr + kb);
        acc = __builtin_amdgcn_mfma_f32_16x16x32_bf16(a, b, acc, 0, 0, 0);
    }
    return acc;
}

__global__ __launch_bounds__(512) void net_main(
    const float* __restrict__ x, const float* __restrict__ xd,
    const float* __restrict__ b1, const float* __restrict__ b2a,
    const float* __restrict__ b2b, const float* __restrict__ b3a,
    const float* __restrict__ b3s, const float* __restrict__ wout,
    const float* __restrict__ scalar, const ushort_t* __restrict__ ws,
    float* __restrict__ out) {
    __shared__ __align__(16) ushort_t sX[RPB * 64];    // bf16 x, swizzled
    __shared__ __align__(16) float sXd[RPB * 64];      // f32 xdot, linear
    __shared__ __align__(16) ushort_t sZ[RPB * H];     // z -> later c2 = 2*p*z
    __shared__ __align__(16) ushort_t sY[RPB * H];     // y1 -> y2
    __shared__ __align__(16) ushort_t sZ12[RPB * H];   // z1_2 -> tz1
    __shared__ __align__(16) ushort_t sZ22[RPB * H];   // z2_2 -> tz2
    __shared__ __align__(16) ushort_t sZ13[RPB * H];   // u = wout*z1_3
    __shared__ __align__(16) ushort_t sZ23[RPB * H];   // z2_3 -> v = wout*z2_3
    __shared__ float sFJ1[RPB * 64];
    __shared__ float sFJ2[RPB * 64];
    __shared__ float sNB[RPB];

    const int tid = threadIdx.x;
    const int wid = tid >> 6;
    const int lane = tid & 63;
    const int row16 = lane & 15;
    const int rq = lane >> 4;
    const int R0 = blockIdx.x * RPB;

    // ---- Phase 0: stage x/xdot, write yy, zero nb accum
    float sc = scalar[0];
    for (int e = tid; e < RPB * 64; e += 512) {
        int r = e >> 6, c = e & 63;
        float xv = x[(R0 + r) * 64 + c];
        sX[r * 64 + (c ^ ((r & 7) << 3))] = f2bf(xv);
        sXd[e] = xd[(R0 + r) * 64 + c];
        out[YY_OFF + (R0 + r) * 64 + c] = sc;
    }
    if (tid < RPB) sNB[tid] = 0.f;
    __syncthreads();

    // ---- Phase 1: z = x@W1.T + b1 ; y1 = z*z
    for (int nt = wid; nt < 16; nt += 8) {
        f32x4 acc = {0.f, 0.f, 0.f, 0.f};
        acc = tile_gemm<64, 64>(sX, ws + O_W1b, lane, nt * 16, acc);
        int c = nt * 16 + row16;
        float bias = b1[c];
#pragma unroll
        for (int i = 0; i < 4; i++) {
            int r = rq * 4 + i;
            int pos = r * H + (c ^ ((r & 7) << 3));
            float z = acc[i] + bias;
            sZ[pos] = f2bf(z);
            sY[pos] = f2bf(z * z);
        }
    }
    __syncthreads();

    // ---- Phase 2: z1_2 = y1@W2a.T + b2a ; z2_2 = y1@W2b.T + b2b (parallel)
    for (int t2 = wid; t2 < 32; t2 += 8) {
        int nt = t2 & 15;
        const ushort_t* W = (t2 < 16) ? (ws + O_W2ab) : (ws + O_W2bb);
        const float* bb = (t2 < 16) ? b2a : b2b;
        ushort_t* dst = (t2 < 16) ? sZ12 : sZ22;
        f32x4 acc = {0.f, 0.f, 0.f, 0.f};
        acc = tile_gemm<H, H>(sY, W, lane, nt * 16, acc);
        int c = nt * 16 + row16;
        float bias = bb[c];
#pragma unroll
        for (int i = 0; i < 4; i++) {
            int r = rq * 4 + i;
            dst[r * H + (c ^ ((r & 7) << 3))] = f2bf(acc[i] + bias);
        }
    }
    __syncthreads();

    // ---- Phase 3: y2 = z1_2 * z2_2 (same swizzle on all buffers -> raw index ok)
    for (int e = tid; e < RPB * H; e += 512)
        sY[e] = f2bf(bf2f(sZ12[e]) * bf2f(sZ22[e]));
    __syncthreads();

    // ---- Phase 4: z2_3 = x@W3s.T + b3s
    for (int nt = wid; nt < 16; nt += 8) {
        f32x4 acc = {0.f, 0.f, 0.f, 0.f};
        acc = tile_gemm<64, 64>(sX, ws + O_W3sb, lane, nt * 16, acc);
        int c = nt * 16 + row16;
        float bias = b3s[c];
#pragma unroll
        for (int i = 0; i < 4; i++) {
            int r = rq * 4 + i;
            sZ23[r * H + (c ^ ((r & 7) << 3))] = f2bf(acc[i] + bias);
        }
    }
    __syncthreads();

    // ---- Phase 5: z1_3 = y2@W3a.T + b3a ; y3 out; u,v; nb reduction
    for (int nt = wid; nt < 16; nt += 8) {
        f32x4 acc = {0.f, 0.f, 0.f, 0.f};
        acc = tile_gemm<H, H>(sY, ws + O_W3ab, lane, nt * 16, acc);
        int c = nt * 16 + row16;
        float bias = b3a[c];
        float wo = wout[c];
#pragma unroll
        for (int i = 0; i < 4; i++) {
            int r = rq * 4 + i;
            int pos = r * H + (c ^ ((r & 7) << 3));
            float z13 = acc[i] + bias;
            float z23 = bf2f(sZ23[pos]);
            float y3 = z13 * z23;
            out[Y_OFF + (R0 + r) * H + c] = y3;
            sZ13[pos] = f2bf(wo * z13);
            sZ23[pos] = f2bf(wo * z23);
            float val = wo * y3;  // contribution to numerical_b
            val += __shfl_xor(val, 1);
            val += __shfl_xor(val, 2);
            val += __shfl_xor(val, 4);
            val += __shfl_xor(val, 8);
            if (row16 == 0) atomicAdd(&sNB[r], val);
        }
    }
    __syncthreads();

    // ---- Phase 6: t = v@W3a (via W3aT); fold into tz1 = t*z1_2, tz2 = t*z2_2
    for (int nt = wid; nt < 16; nt += 8) {
        f32x4 acc = {0.f, 0.f, 0.f, 0.f};
        acc = tile_gemm<H, H>(sZ23, ws + O_W3aT, lane, nt * 16, acc);
        int c = nt * 16 + row16;
#pragma unroll
        for (int i = 0; i < 4; i++) {
            int r = rq * 4 + i;
            int pos = r * H + (c ^ ((r & 7) << 3));
            float t = acc[i];
            float z12o = bf2f(sZ12[pos]);
            float z22o = bf2f(sZ22[pos]);
            sZ12[pos] = f2bf(t * z12o);
            sZ22[pos] = f2bf(t * z22o);
        }
    }
    __syncthreads();

    // ---- Phase 7: p = tz1@W2b + tz2@W2a (via transposed copies); c2 = 2*p*z
    for (int nt = wid; nt < 16; nt += 8) {
        f32x4 acc = {0.f, 0.f, 0.f, 0.f};
        acc = tile_gemm<H, H>(sZ12, ws + O_W2bT, lane, nt * 16, acc);
        acc = tile_gemm<H, H>(sZ22, ws + O_W2aT, lane, nt * 16, acc);
        int c = nt * 16 + row16;
#pragma unroll
        for (int i = 0; i < 4; i++) {
            int r = rq * 4 + i;
            int pos = r * H + (c ^ ((r & 7) << 3));
            sZ[pos] = f2bf(2.f * acc[i] * bf2f(sZ[pos]));
        }
    }
    __syncthreads();

    // ---- Phase 8: fj1 = u@W3s (W3sT), fj2 = c2@W1 (W1T); N=64 each
    if (wid < 4) {
        f32x4 acc = {0.f, 0.f, 0.f, 0.f};
        acc = tile_gemm<H, H>(sZ13, ws + O_W3sT, lane, wid * 16, acc);
        int c = wid * 16 + row16;
#pragma unroll
        for (int i = 0; i < 4; i++) sFJ1[(rq * 4 + i) * 64 + c] = acc[i];
    } else {
        f32x4 acc = {0.f, 0.f, 0.f, 0.f};
        acc = tile_gemm<H, H>(sZ, ws + O_W1T, lane, (wid - 4) * 16, acc);
        int c = (wid - 4) * 16 + row16;
#pragma unroll
        for (int i = 0; i < 4; i++) sFJ2[(rq * 4 + i) * 64 + c] = acc[i];
    }
    __syncthreads();

    // ---- Phase 9: bdot[r] = sum_i (fj1+fj2)[r,i]*xdot[r,i]; write nb
    {
        int r = tid >> 5, j = tid & 31;
        float s = (sFJ1[r * 64 + j] + sFJ2[r * 64 + j]) * sXd[r * 64 + j] +
                  (sFJ1[r * 64 + j + 32] + sFJ2[r * 64 + j + 32]) * sXd[r * 64 + j + 32];
        s += __shfl_xor(s, 1, 32);
        s += __shfl_xor(s, 2, 32);
        s += __shfl_xor(s, 4, 32);
        s += __shfl_xor(s, 8, 32);
        s += __shfl_xor(s, 16, 32);
        if (j == 0) out[BDOT_OFF + R0 + r] = s;
        if (tid < RPB) out[NB_OFF + R0 + tid] = sNB[tid];
    }
}

extern "C" void kernel_launch(void* const* d_in, const int* in_sizes, int n_in,
                              void* d_out, int out_size, void* d_ws, size_t ws_size,
                              hipStream_t stream) {
    (void)in_sizes; (void)n_in; (void)out_size; (void)ws_size;
    const float* x = (const float*)d_in[0];
    const float* xd = (const float*)d_in[1];
    const float* w1 = (const float*)d_in[2];
    const float* b1 = (const float*)d_in[3];
    const float* w2a = (const float*)d_in[4];
    const float* b2a = (const float*)d_in[5];
    const float* w2b = (const float*)d_in[6];
    const float* b2b = (const float*)d_in[7];
    const float* w3a = (const float*)d_in[8];
    const float* b3a = (const float*)d_in[9];
    const float* w3s = (const float*)d_in[10];
    const float* b3s = (const float*)d_in[11];
    const float* wout = (const float*)d_in[12];
    const float* scalar = (const float*)d_in[13];
    ushort_t* ws = (ushort_t*)d_ws;
    float* out = (float*)d_out;

    prep_weights<<<256, 256, 0, stream>>>(w1, w2a, w2b, w3a, w3s, ws);
    net_main<<<256, 512, 0, stream>>>(x, xd, b1, b2a, b2b, b3a, b3s, wout, scalar, ws, out);
}